// Round 17
// baseline (245.175 us; speedup 1.0000x reference)
//
#include <hip/hip_runtime.h>
#include <cstdint>
#include <cstddef>

#define NN 100000
#define EE 1600000
#define DIM 128
#define CAP 48        // ELL row capacity (mean deg 16; P(deg>48) ~ 5e-11 per node)
#define OVF_CAP 512   // overflow edge capacity (expected 0 used)

#define NB 391        // dst buckets of 256 nodes: ceil(100000/256)
#define BCAP 4608     // per-bucket partition capacity (mean 4092, +8 sigma)
#define SLOTS 32      // LDS staging slots per bucket
#define FLUSH_AT 16   // flush threshold (entries)
#define ACHUNK 4096   // edges per phase-A partition block
#define ATHREADS 512

#define NPREP_W 128                          // weight-prep blocks (65536/512)
#define NPREP_X ((NN * DIM / 4) / ATHREADS)  // x-cast blocks (6250)

#if __has_builtin(__builtin_amdgcn_cvt_pk_f32_fp8) && __has_builtin(__builtin_amdgcn_cvt_pk_fp8_f32)
#define HAVE_FP8 1
#else
#define HAVE_FP8 0
#endif

typedef __attribute__((ext_vector_type(8))) short bf16x8;
typedef __attribute__((ext_vector_type(4))) float f32x4;
typedef __attribute__((ext_vector_type(2))) float f32x2;

__device__ __forceinline__ unsigned short f2bf(float f) {
  union { float f; uint32_t u; } v; v.f = f;
  uint32_t r = v.u + 0x7FFF + ((v.u >> 16) & 1);  // RNE to bf16
  return (unsigned short)(r >> 16);
}
__device__ __forceinline__ uint32_t pk2(float a, float b) {
  return (uint32_t)f2bf(a) | ((uint32_t)f2bf(b) << 16);
}

// ---- fp8 e4m3fn helpers (HW path + software fallback) ----------------------
// NOTE: the builtin's word-select arg must be a LITERAL constant -> template.
template <bool HI>
__device__ __forceinline__ uint32_t f2fp8_pair(float a, float b, uint32_t old) {
#if HAVE_FP8
  return (uint32_t)__builtin_amdgcn_cvt_pk_fp8_f32(a, b, (int)old, HI);
#else
  auto enc = [](float f) -> uint32_t {
    union { float f; uint32_t u; } v; v.f = f;
    uint32_t s = (v.u >> 31) << 7;
    uint32_t m = v.u & 0x7FFFFFFF;
    if (m < 0x3C000000u) {  // < 2^-7: subnormal territory
      union { uint32_t u; float f; } w; w.u = m;
      int q = (int)(w.f * 512.0f + 0.5f);
      if (q > 7) return s | (1u << 3);
      return s | (uint32_t)q;
    }
    uint32_t u2 = m + 0x00080000u;  // round into mantissa bit 20
    int e = (int)(u2 >> 23) - 127;
    if (e > 8) return s | 0x7E;  // clamp to 448
    return s | ((uint32_t)(e + 7) << 3) | ((u2 >> 20) & 7);
  };
  uint32_t pr = enc(a) | (enc(b) << 8);
  return HI ? ((old & 0x0000FFFFu) | (pr << 16)) : ((old & 0xFFFF0000u) | pr);
#endif
}

// 8 fp8 -> 4 packed f32x2 accumulators (v_pk_add_f32 on the adds)
__device__ __forceinline__ void acc_fp8x8_pk(f32x2* s, uint2 w) {
#if HAVE_FP8
  s[0] += __builtin_amdgcn_cvt_pk_f32_fp8((int)w.x, false);
  s[1] += __builtin_amdgcn_cvt_pk_f32_fp8((int)w.x, true);
  s[2] += __builtin_amdgcn_cvt_pk_f32_fp8((int)w.y, false);
  s[3] += __builtin_amdgcn_cvt_pk_f32_fp8((int)w.y, true);
#else
  auto dec = [](uint32_t b) -> float {
    uint32_t sg = (b >> 7) & 1, e = (b >> 3) & 15, m = b & 7;
    if (e == 0) return (sg ? -1.f : 1.f) * (float)m * 0.001953125f;  // m * 2^-9
    union { uint32_t u; float f; } w;
    w.u = (sg << 31) | ((e + 120) << 23) | (m << 20);
    return w.f;
  };
#pragma unroll
  for (int i = 0; i < 4; ++i) s[i / 2][i & 1] += dec((w.x >> (i * 8)) & 0xFF);
#pragma unroll
  for (int i = 0; i < 4; ++i) s[2 + i / 2][i & 1] += dec((w.y >> (i * 8)) & 0xFF);
#endif
}

// ---------------------------------------------------------------------------
// partA_prep: blocks < NB partition edges into dst-buckets (LDS staging,
// per-thread flush -- round-7 proved wave-serial flush regresses 3x);
// blocks >= NB do prep (weight transpose+bf16 cast, x -> bf16 + fp8 planes).
// pack = s | ((d & 255) << 17)   (s < 2^17)
// ---------------------------------------------------------------------------
__global__ __launch_bounds__(ATHREADS) void partA_prep_kernel(
    const void* __restrict__ edges, int* __restrict__ bcnt,
    unsigned* __restrict__ part, int* __restrict__ novf, int* __restrict__ ovf,
    const float* __restrict__ x,
    const float* __restrict__ W1l, const float* __restrict__ W1r,
    const float* __restrict__ W2l, const float* __restrict__ W2r,
    unsigned short* __restrict__ Wt1, unsigned short* __restrict__ Wt2,
    unsigned short* __restrict__ xb, unsigned char* __restrict__ x8) {
  __shared__ unsigned stage[NB][SLOTS + 1];  // +1 pad: de-alias flush banks
  __shared__ int scnt[NB];
  __shared__ int sh_i64;
  const int t = threadIdx.x;

  if (blockIdx.x >= NB) {  // ---- prep path (no LDS use) ----
    int bid = blockIdx.x - NB;
    if (bid < NPREP_W) {
      int idx = bid * ATHREADS + t;  // 65536 total
      int layer = idx >> 15;
      int rest = idx & 32767;
      int mat = rest >> 14;
      int r = rest & 16383;
      int k = r >> 7, n = r & 127;
      const float* W = layer ? (mat ? W2r : W2l) : (mat ? W1r : W1l);
      unsigned short* Wt = layer ? Wt2 : Wt1;
      Wt[((size_t)(mat * 128 + n)) * 128 + k] = f2bf(W[k * 128 + n]);
    } else {
      int i = (bid - NPREP_W) * ATHREADS + t;  // one float4 per thread
      if (i < NN * DIM / 4) {
        f32x4 v = ((const f32x4*)x)[i];
        ushort4 hb;
        hb.x = f2bf(v[0]); hb.y = f2bf(v[1]); hb.z = f2bf(v[2]); hb.w = f2bf(v[3]);
        ((ushort4*)xb)[i] = hb;
        uint32_t pk = f2fp8_pair<false>(v[0], v[1], 0);
        pk = f2fp8_pair<true>(v[2], v[3], pk);
        ((uint32_t*)x8)[i] = pk;
      }
    }
    return;
  }

  // ---- partition path ----
  for (int b = t; b < NB; b += ATHREADS) scnt[b] = 0;
  if (t < 64) {
    // int64 little-endian => odd 32-bit words of first 64 entries all zero;
    // int32 => those words are random src values, all-zero impossible.
    int v = ((const int*)edges)[2 * t + 1];
    unsigned long long m = __ballot(v != 0);
    if (t == 0) sh_i64 = (m == 0ull) ? 1 : 0;
  }
  __syncthreads();
  const int i64 = sh_i64;
  const long long ebase = (long long)blockIdx.x * ACHUNK;
  const int nrounds = ACHUNK / ATHREADS;
  for (int r = 0; r < nrounds; ++r) {
    long long e = ebase + (long long)r * ATHREADS + t;
    if (e < EE) {
      int s, d;
      if (i64) {
        s = (int)((const long long*)edges)[e];
        d = (int)((const long long*)edges)[(long long)EE + e];
      } else {
        s = ((const int*)edges)[e];
        d = ((const int*)edges)[(long long)EE + e];
      }
      if ((unsigned)s < NN && (unsigned)d < NN) {
        int b = d >> 8;
        unsigned pk = (unsigned)s | ((unsigned)(d & 255) << 17);
        int pos = atomicAdd(&scnt[b], 1);
        if (pos < SLOTS) {
          stage[b][pos] = pk;
        } else {  // stage overflow (rare): direct append
          int g = atomicAdd(&bcnt[b], 1);
          if (g < BCAP) part[(size_t)b * BCAP + g] = pk;
          else { int oi = atomicAdd(novf, 1); if (oi < OVF_CAP) { ovf[oi*2] = s; ovf[oi*2+1] = d; } }
        }
      }
    }
    __syncthreads();
    const bool last = (r == nrounds - 1);
    for (int b = t; b < NB; b += ATHREADS) {  // per-thread flush (parallel chains)
      int c = scnt[b];
      if (c > SLOTS) c = SLOTS;
      if (c > 0 && (last || c >= FLUSH_AT)) {
        int g = atomicAdd(&bcnt[b], c);
        for (int i = 0; i < c; ++i) {
          int gp = g + i;
          unsigned pk = stage[b][i];
          if (gp < BCAP) {
            part[(size_t)b * BCAP + gp] = pk;
          } else {
            int oi = atomicAdd(novf, 1);
            if (oi < OVF_CAP) { ovf[oi*2] = (int)(pk & 0x1FFFF); ovf[oi*2+1] = (b << 8) | (int)(pk >> 17); }
          }
        }
        scnt[b] = 0;
      }
    }
    __syncthreads();
  }
}

// ---------------------------------------------------------------------------
// Phase B: per bucket (256 nodes), build ELL rows in LDS (LDS atomics),
// write densely coalesced. ELL entries stored PRE-SCALED (s << 7 = fp8-row
// byte offset) so gather's address chain is a single 64-bit add.
// ---------------------------------------------------------------------------
__global__ __launch_bounds__(256) void partB_kernel(
    const int* __restrict__ bcnt, const unsigned* __restrict__ part,
    int* __restrict__ cnt, int* __restrict__ ell,
    int* __restrict__ novf, int* __restrict__ ovf) {
  __shared__ int lcnt[256];
  __shared__ int lell[256 * CAP];  // 48 KB
  const int t = threadIdx.x;
  const int b = blockIdx.x;
  lcnt[t] = 0;
  __syncthreads();
  int n = bcnt[b];
  if (n > BCAP) n = BCAP;
  for (int i = t; i < n; i += 256) {
    unsigned pk = part[(size_t)b * BCAP + i];
    int s = (int)(pk & 0x1FFFF);
    int dl = (int)(pk >> 17);
    int pos = atomicAdd(&lcnt[dl], 1);
    if (pos < CAP) lell[dl * CAP + pos] = s << 7;  // byte offset into fp8 plane
    else { int oi = atomicAdd(novf, 1); if (oi < OVF_CAP) { ovf[oi*2] = s; ovf[oi*2+1] = (b << 8) | dl; } }
  }
  __syncthreads();
  int4* dst = (int4*)(ell + (size_t)b * 256 * CAP);
  const int4* src = (const int4*)lell;
#pragma unroll
  for (int i = 0; i < 256 * CAP / 4 / 256; ++i) dst[t + i * 256] = src[t + i * 256];
  int node = b * 256 + t;
  if (node < NN) cnt[node] = lcnt[t];
}

// ---------------------------------------------------------------------------
// Gather-aggregate from ELL over fp8 rows (128 B = ONE cache line per nbr).
// One wave per node; quarter-wave per neighbor row (lane = q*16+l, lane owns
// cols l*8..l*8+7 as uint2). 4-deep unroll -> 16 rows in flight per wave.
// ELL entries are pre-scaled byte offsets; accumulation is f32x2-packed
// (v_pk_add_f32) -- inner VALU 12 -> 8 per row.
// ---------------------------------------------------------------------------
__global__ __launch_bounds__(256) void gather_ell_kernel(
    const int* __restrict__ cnt, const int* __restrict__ ell,
    const unsigned char* __restrict__ h8, unsigned short* __restrict__ ahi,
    const int* __restrict__ novf, const int* __restrict__ ovf) {
  const int node = blockIdx.x * 4 + (threadIdx.x >> 6);
  const int lane = threadIdx.x & 63;
  const int q = lane >> 4;       // quarter 0..3
  const int l = lane & 15;       // lane-in-quarter: cols l*8..l*8+7
  if (node >= NN) return;
  const int dcnt = cnt[node];
  const int n = dcnt < CAP ? dcnt : CAP;
  const int* row = ell + (size_t)node * CAP;
  const unsigned char* hl = h8 + l * 8;
  f32x2 s[4] = {{0.f, 0.f}, {0.f, 0.f}, {0.f, 0.f}, {0.f, 0.f}};
  int p = q;
  for (; p + 12 < n; p += 16) {  // 4 independent row loads in flight
    uint2 w0 = *(const uint2*)(hl + (unsigned)row[p]);
    uint2 w1 = *(const uint2*)(hl + (unsigned)row[p + 4]);
    uint2 w2 = *(const uint2*)(hl + (unsigned)row[p + 8]);
    uint2 w3 = *(const uint2*)(hl + (unsigned)row[p + 12]);
    acc_fp8x8_pk(s, w0);
    acc_fp8x8_pk(s, w1);
    acc_fp8x8_pk(s, w2);
    acc_fp8x8_pk(s, w3);
  }
  for (; p < n; p += 4) {
    uint2 w0 = *(const uint2*)(hl + (unsigned)row[p]);
    acc_fp8x8_pk(s, w0);
  }
#pragma unroll
  for (int i = 0; i < 4; ++i) {
#pragma unroll
    for (int j = 0; j < 2; ++j) {
      s[i][j] += __shfl_xor(s[i][j], 16, 64);
      s[i][j] += __shfl_xor(s[i][j], 32, 64);
    }
  }
  if (q == 0) {
    if (dcnt > CAP) {  // overflow fixup: scan tiny list (expected empty)
      int no = *novf;
      if (no > OVF_CAP) no = OVF_CAP;
      for (int i = 0; i < no; ++i) {
        if (ovf[i * 2 + 1] == node) {
          uint2 w0 = *(const uint2*)(hl + ((unsigned)ovf[i * 2] << 7));
          acc_fp8x8_pk(s, w0);
        }
      }
    }
    const float rd = 1.0f / fmaxf((float)dcnt, 1.0f);
    uint4 o;
    o.x = pk2(s[0][0] * rd, s[0][1] * rd);
    o.y = pk2(s[1][0] * rd, s[1][1] * rd);
    o.z = pk2(s[2][0] * rd, s[2][1] * rd);
    o.w = pk2(s[3][0] * rd, s[3][1] * rd);
    *(uint4*)(ahi + (size_t)node * DIM + l * 8) = o;
  }
}

// ---------------------------------------------------------------------------
// Dense via MFMA: out = act(agg_bf16 @ Wl + bl + h_bf16 @ Wr).
// Pure bf16-plane loads (2 x 16B per fragment pair -> 4 MFMAs), no in-loop
// conversion (round-14's f32-load + cvt chain halved dense throughput).
// WP (layer 1): epilogue writes result IN-PLACE over hb (bf16) and h8 (fp8)
//   -- safe: each block reads only its own 64 rows (before __syncthreads);
//   gather-1 has already completed; no other block reads these rows.
// WOUT (layer 2): writes f32 out only.
// ---------------------------------------------------------------------------
template <bool RELU, bool WP, bool WOUT>
__global__ __launch_bounds__(256, 2) void dense_mfma_kernel(
    const unsigned short* __restrict__ ahi, unsigned short* hb,
    const unsigned short* __restrict__ Wt, const float* __restrict__ bl,
    float* __restrict__ out, unsigned char* ph8, int n) {
  const int t = threadIdx.x;
  const int wave = t >> 6, lane = t & 63;
  const int l15 = lane & 15, l4 = lane >> 4;
  const int base = blockIdx.x * 64;

  bf16x8 bfr[2][4][2];
#pragma unroll
  for (int mat = 0; mat < 2; ++mat)
#pragma unroll
    for (int kt = 0; kt < 4; ++kt)
#pragma unroll
      for (int ntl = 0; ntl < 2; ++ntl) {
        int ncol = (wave * 2 + ntl) * 16 + l15;
        int k0 = kt * 32 + l4 * 8;
        bfr[mat][kt][ntl] = *(const bf16x8*)(Wt + ((size_t)(mat * 128 + ncol)) * 128 + k0);
      }

  f32x4 acc[4][2];
#pragma unroll
  for (int ntl = 0; ntl < 2; ++ntl) {
    float b = bl[(wave * 2 + ntl) * 16 + l15];
#pragma unroll
    for (int rt = 0; rt < 4; ++rt) {
      f32x4 ib = {b, b, b, b};
      acc[rt][ntl] = ib;
    }
  }

#pragma unroll
  for (int kt = 0; kt < 4; ++kt) {
    const int k0 = kt * 32 + l4 * 8;
#pragma unroll
    for (int rt = 0; rt < 4; ++rt) {
      int row = base + rt * 16 + l15;
      if (row >= n) row = n - 1;  // clamp: padded rows computed but never stored
      const size_t off = (size_t)row * DIM + k0;
      bf16x8 a8 = *(const bf16x8*)(ahi + off);
      bf16x8 hh8 = *(const bf16x8*)(hb + off);
#pragma unroll
      for (int ntl = 0; ntl < 2; ++ntl) {
        acc[rt][ntl] = __builtin_amdgcn_mfma_f32_16x16x32_bf16(a8, bfr[0][kt][ntl], acc[rt][ntl], 0, 0, 0);
        acc[rt][ntl] = __builtin_amdgcn_mfma_f32_16x16x32_bf16(hh8, bfr[1][kt][ntl], acc[rt][ntl], 0, 0, 0);
      }
    }
  }

  __syncthreads();  // all hb reads complete before the in-place plane writes

#pragma unroll
  for (int rt = 0; rt < 4; ++rt)
#pragma unroll
    for (int ntl = 0; ntl < 2; ++ntl) {
      const int col = (wave * 2 + ntl) * 16 + l15;
#pragma unroll
      for (int r = 0; r < 4; ++r) {
        int row = base + rt * 16 + l4 * 4 + r;
        if (row < n) {
          float v = acc[rt][ntl][r];
          if (RELU) v = fmaxf(v, 0.f);
          const size_t off = (size_t)row * DIM + col;
          if (WOUT) out[off] = v;
          if (WP) {
            hb[off] = f2bf(v);
            ph8[off] = (unsigned char)(f2fp8_pair<false>(v, v, 0) & 0xFF);
          }
        }
      }
    }
}

// ---------------------------------------------------------------------------
extern "C" void kernel_launch(void* const* d_in, const int* in_sizes, int n_in,
                              void* d_out, int out_size, void* d_ws, size_t ws_size,
                              hipStream_t stream) {
  const float* x   = (const float*)d_in[0];
  const void* edges = d_in[1];
  const float* W1l = (const float*)d_in[2];
  const float* b1l = (const float*)d_in[3];
  const float* W1r = (const float*)d_in[4];
  const float* W2l = (const float*)d_in[5];
  const float* b2l = (const float*)d_in[6];
  const float* W2r = (const float*)d_in[7];
  float* out = (float*)d_out;

  // ---- workspace layout (~84 MB)
  //  * part (7.2 MB) aliases ahi (25.6 MB): part dead after partB, ahi first
  //    written by gather-1.
  //  * h1 planes overwrite x planes IN-PLACE in dense-1's epilogue (each
  //    block touches only rows it already consumed; gather-1 done).
  char* p = (char*)d_ws;
  unsigned short* Wt1 = (unsigned short*)p;               p += 2 * 128 * 128 * 2;
  unsigned short* Wt2 = (unsigned short*)p;               p += 2 * 128 * 128 * 2;
  int* cnt  = (int*)p;                                    p += (size_t)NN * 4;
  int* bcnt = (int*)p;                                    p += (size_t)NB * 4;
  int* novf = (int*)p;                                    p += 4;
  p = (char*)(((uintptr_t)p + 15) & ~(uintptr_t)15);
  int* ovf = (int*)p;                                     p += (size_t)OVF_CAP * 2 * 4;
  p = (char*)(((uintptr_t)p + 255) & ~(uintptr_t)255);
  int* ell = (int*)p;                                     p += (size_t)NB * 256 * CAP * 4;
  p = (char*)(((uintptr_t)p + 255) & ~(uintptr_t)255);
  unsigned short* ahi = (unsigned short*)p;               p += (size_t)NN * DIM * 2;
  unsigned short* hb = (unsigned short*)p;                p += (size_t)NN * DIM * 2;  // x/h1 bf16
  unsigned char* h8 = (unsigned char*)p;                  p += (size_t)NN * DIM;      // x/h1 fp8
  unsigned* part = (unsigned*)ahi;  // alias (disjoint lifetimes)

  // zero bcnt + novf in one memset (cnt fully rewritten by partB)
  (void)hipMemsetAsync(bcnt, 0, ((size_t)NB + 1) * 4, stream);

  // partition + weight/x prep in one grid (prep fills idle CUs)
  partA_prep_kernel<<<NB + NPREP_W + NPREP_X, ATHREADS, 0, stream>>>(
      edges, bcnt, part, novf, ovf, x, W1l, W1r, W2l, W2r, Wt1, Wt2, hb, h8);
  partB_kernel<<<NB, 256, 0, stream>>>(bcnt, part, cnt, ell, novf, ovf);

  const int gather_blocks = (NN + 3) / 4;
  const int dense_blocks = (NN + 63) / 64;

  // ---- layer 1: h1 = relu(mean_agg(x) @ W1l + b1l + x @ W1r)
  //      -> bf16 plane (over hb) + fp8 plane (over h8); no f32 write
  gather_ell_kernel<<<gather_blocks, 256, 0, stream>>>(cnt, ell, h8, ahi, novf, ovf);
  dense_mfma_kernel<true, true, false><<<dense_blocks, 256, 0, stream>>>(
      ahi, hb, Wt1, b1l, out, h8, NN);

  // ---- layer 2: out = mean_agg(h1) @ W2l + b2l + h1 @ W2r -> f32 out
  gather_ell_kernel<<<gather_blocks, 256, 0, stream>>>(cnt, ell, h8, ahi, novf, ovf);
  dense_mfma_kernel<false, false, true><<<dense_blocks, 256, 0, stream>>>(
      ahi, hb, Wt2, b2l, out, nullptr, NN);
}

// Round 18
// 235.519 us; speedup vs baseline: 1.0410x; 1.0410x over previous
//
#include <hip/hip_runtime.h>
#include <cstdint>
#include <cstddef>

#define NN 100000
#define EE 1600000
#define DIM 128
#define CAP 48        // ELL row capacity (mean deg 16; P(deg>48) ~ 5e-11 per node)
#define OVF_CAP 512   // overflow edge capacity (expected 0 used)

#define NB 391        // dst buckets of 256 nodes: ceil(100000/256)
#define ACHUNK 4096   // edges per partition block
#define EDGE_BLKS 391 // ceil(EE / ACHUNK)
#define SEG 40        // private per-(bucket,block) segment capacity (mean 10.5)
#define ATHREADS 512

#define NPREP_W 128                          // weight-prep blocks (65536/512)
#define NPREP_X ((NN * DIM / 4) / ATHREADS)  // x-cast blocks (6250)

#if __has_builtin(__builtin_amdgcn_cvt_pk_f32_fp8) && __has_builtin(__builtin_amdgcn_cvt_pk_fp8_f32)
#define HAVE_FP8 1
#else
#define HAVE_FP8 0
#endif

typedef __attribute__((ext_vector_type(8))) short bf16x8;
typedef __attribute__((ext_vector_type(4))) float f32x4;
typedef __attribute__((ext_vector_type(2))) float f32x2;

__device__ __forceinline__ unsigned short f2bf(float f) {
  union { float f; uint32_t u; } v; v.f = f;
  uint32_t r = v.u + 0x7FFF + ((v.u >> 16) & 1);  // RNE to bf16
  return (unsigned short)(r >> 16);
}
__device__ __forceinline__ uint32_t pk2(float a, float b) {
  return (uint32_t)f2bf(a) | ((uint32_t)f2bf(b) << 16);
}

// ---- fp8 e4m3fn helpers (HW path + software fallback) ----------------------
// NOTE: the builtin's word-select arg must be a LITERAL constant -> template.
template <bool HI>
__device__ __forceinline__ uint32_t f2fp8_pair(float a, float b, uint32_t old) {
#if HAVE_FP8
  return (uint32_t)__builtin_amdgcn_cvt_pk_fp8_f32(a, b, (int)old, HI);
#else
  auto enc = [](float f) -> uint32_t {
    union { float f; uint32_t u; } v; v.f = f;
    uint32_t s = (v.u >> 31) << 7;
    uint32_t m = v.u & 0x7FFFFFFF;
    if (m < 0x3C000000u) {  // < 2^-7: subnormal territory
      union { uint32_t u; float f; } w; w.u = m;
      int q = (int)(w.f * 512.0f + 0.5f);
      if (q > 7) return s | (1u << 3);
      return s | (uint32_t)q;
    }
    uint32_t u2 = m + 0x00080000u;  // round into mantissa bit 20
    int e = (int)(u2 >> 23) - 127;
    if (e > 8) return s | 0x7E;  // clamp to 448
    return s | ((uint32_t)(e + 7) << 3) | ((u2 >> 20) & 7);
  };
  uint32_t pr = enc(a) | (enc(b) << 8);
  return HI ? ((old & 0x0000FFFFu) | (pr << 16)) : ((old & 0xFFFF0000u) | pr);
#endif
}

// round-16 scalar accumulate (8 independent f32 chains -- round-17's packed
// variant REGRESSED: longer cvt->pk_add dependency chains)
__device__ __forceinline__ void acc_fp8x8(float* s, uint2 w) {
#if HAVE_FP8
  f32x2 f;
  f = __builtin_amdgcn_cvt_pk_f32_fp8((int)w.x, false); s[0] += f.x; s[1] += f.y;
  f = __builtin_amdgcn_cvt_pk_f32_fp8((int)w.x, true);  s[2] += f.x; s[3] += f.y;
  f = __builtin_amdgcn_cvt_pk_f32_fp8((int)w.y, false); s[4] += f.x; s[5] += f.y;
  f = __builtin_amdgcn_cvt_pk_f32_fp8((int)w.y, true);  s[6] += f.x; s[7] += f.y;
#else
  auto dec = [](uint32_t b) -> float {
    uint32_t sg = (b >> 7) & 1, e = (b >> 3) & 15, m = b & 7;
    if (e == 0) return (sg ? -1.f : 1.f) * (float)m * 0.001953125f;  // m * 2^-9
    union { uint32_t u; float f; } w;
    w.u = (sg << 31) | ((e + 120) << 23) | (m << 20);
    return w.f;
  };
#pragma unroll
  for (int i = 0; i < 4; ++i) s[i] += dec((w.x >> (i * 8)) & 0xFF);
#pragma unroll
  for (int i = 0; i < 4; ++i) s[4 + i] += dec((w.y >> (i * 8)) & 0xFF);
#endif
}

// ---------------------------------------------------------------------------
// partA_prep: blocks < EDGE_BLKS partition edges into PRIVATE per-(bucket,
// block) segments -- zero global atomics, zero flush loops, zero intermediate
// barriers, 1.6 KB LDS. Per edge: coalesced load -> LDS atomicAdd cursor ->
// fire-and-forget 4 B store. bcnt2[bucket][block] written once at the end.
// Blocks >= EDGE_BLKS do prep (weight transpose+bf16, x -> bf16+fp8 planes).
// pack = s | ((d & 255) << 17)   (s < 2^17)
// ---------------------------------------------------------------------------
__global__ __launch_bounds__(ATHREADS) void partA_prep_kernel(
    const void* __restrict__ edges, int* __restrict__ bcnt2,
    unsigned* __restrict__ part, int* __restrict__ novf, int* __restrict__ ovf,
    const float* __restrict__ x,
    const float* __restrict__ W1l, const float* __restrict__ W1r,
    const float* __restrict__ W2l, const float* __restrict__ W2r,
    unsigned short* __restrict__ Wt1, unsigned short* __restrict__ Wt2,
    unsigned short* __restrict__ xb, unsigned char* __restrict__ x8) {
  __shared__ int cnt391[NB];
  __shared__ int sh_i64;
  const int t = threadIdx.x;

  if (blockIdx.x >= EDGE_BLKS) {  // ---- prep path ----
    int bid = blockIdx.x - EDGE_BLKS;
    if (bid < NPREP_W) {
      int idx = bid * ATHREADS + t;  // 65536 total
      int layer = idx >> 15;
      int rest = idx & 32767;
      int mat = rest >> 14;
      int r = rest & 16383;
      int k = r >> 7, n = r & 127;
      const float* W = layer ? (mat ? W2r : W2l) : (mat ? W1r : W1l);
      unsigned short* Wt = layer ? Wt2 : Wt1;
      Wt[((size_t)(mat * 128 + n)) * 128 + k] = f2bf(W[k * 128 + n]);
    } else {
      int i = (bid - NPREP_W) * ATHREADS + t;  // one float4 per thread
      if (i < NN * DIM / 4) {
        f32x4 v = ((const f32x4*)x)[i];
        ushort4 hb;
        hb.x = f2bf(v[0]); hb.y = f2bf(v[1]); hb.z = f2bf(v[2]); hb.w = f2bf(v[3]);
        ((ushort4*)xb)[i] = hb;
        uint32_t pk = f2fp8_pair<false>(v[0], v[1], 0);
        pk = f2fp8_pair<true>(v[2], v[3], pk);
        ((uint32_t*)x8)[i] = pk;
      }
    }
    return;
  }

  // ---- partition path ----
  for (int b = t; b < NB; b += ATHREADS) cnt391[b] = 0;
  if (t < 64) {
    // int64 little-endian => odd 32-bit words of first 64 entries all zero;
    // int32 => those words are random src values, all-zero impossible.
    int v = ((const int*)edges)[2 * t + 1];
    unsigned long long m = __ballot(v != 0);
    if (t == 0) sh_i64 = (m == 0ull) ? 1 : 0;
  }
  __syncthreads();
  const int i64 = sh_i64;
  const long long ebase = (long long)blockIdx.x * ACHUNK;
#pragma unroll
  for (int r = 0; r < ACHUNK / ATHREADS; ++r) {
    long long e = ebase + (long long)r * ATHREADS + t;
    if (e < EE) {
      int s, d;
      if (i64) {
        s = (int)((const long long*)edges)[e];
        d = (int)((const long long*)edges)[(long long)EE + e];
      } else {
        s = ((const int*)edges)[e];
        d = ((const int*)edges)[(long long)EE + e];
      }
      if ((unsigned)s < NN && (unsigned)d < NN) {
        int b = d >> 8;
        unsigned pk = (unsigned)s | ((unsigned)(d & 255) << 17);
        int pos = atomicAdd(&cnt391[b], 1);
        if (pos < SEG) {
          part[((size_t)b * EDGE_BLKS + blockIdx.x) * SEG + pos] = pk;
        } else {  // segment overflow (P ~ 2e-8 per launch): spill to ovf list
          int oi = atomicAdd(novf, 1);
          if (oi < OVF_CAP) { ovf[oi * 2] = s; ovf[oi * 2 + 1] = d; }
        }
      }
    }
  }
  __syncthreads();
  for (int b = t; b < NB; b += ATHREADS) {
    int c = cnt391[b];
    bcnt2[(size_t)b * EDGE_BLKS + blockIdx.x] = c < SEG ? c : SEG;
  }
}

// ---------------------------------------------------------------------------
// Phase B: per bucket (256 nodes), scan the bucket's 391 private segments
// (contiguous 62.5 KB window), build ELL rows in LDS (LDS atomics), write
// densely coalesced. Also emits cnt (degree).
// ---------------------------------------------------------------------------
__global__ __launch_bounds__(256) void partB_kernel(
    const int* __restrict__ bcnt2, const unsigned* __restrict__ part,
    int* __restrict__ cnt, int* __restrict__ ell,
    int* __restrict__ novf, int* __restrict__ ovf) {
  __shared__ int lcnt[256];
  __shared__ int lell[256 * CAP];  // 48 KB
  const int t = threadIdx.x;
  const int b = blockIdx.x;
  lcnt[t] = 0;
  __syncthreads();
  for (int blk = t; blk < EDGE_BLKS; blk += 256) {
    int c = bcnt2[(size_t)b * EDGE_BLKS + blk];
    const unsigned* seg = part + ((size_t)b * EDGE_BLKS + blk) * SEG;
    for (int i = 0; i < c; ++i) {
      unsigned pk = seg[i];
      int s = (int)(pk & 0x1FFFF);
      int dl = (int)(pk >> 17);
      int pos = atomicAdd(&lcnt[dl], 1);
      if (pos < CAP) lell[dl * CAP + pos] = s;
      else { int oi = atomicAdd(novf, 1); if (oi < OVF_CAP) { ovf[oi*2] = s; ovf[oi*2+1] = (b << 8) | dl; } }
    }
  }
  __syncthreads();
  int4* dst = (int4*)(ell + (size_t)b * 256 * CAP);
  const int4* src = (const int4*)lell;
#pragma unroll
  for (int i = 0; i < 256 * CAP / 4 / 256; ++i) dst[t + i * 256] = src[t + i * 256];
  int node = b * 256 + t;
  if (node < NN) cnt[node] = lcnt[t];
}

// ---------------------------------------------------------------------------
// Gather-aggregate from ELL over fp8 rows (128 B = ONE cache line per nbr).
// Round-16 form (empirical optimum): one wave per node; quarter-wave per
// neighbor row; 4-deep unroll -> 16 rows in flight; 8 independent scalar
// f32 accumulators; writes bf16 agg plane.
// ---------------------------------------------------------------------------
__global__ __launch_bounds__(256) void gather_ell_kernel(
    const int* __restrict__ cnt, const int* __restrict__ ell,
    const unsigned char* __restrict__ h8, unsigned short* __restrict__ ahi,
    const int* __restrict__ novf, const int* __restrict__ ovf) {
  const int node = blockIdx.x * 4 + (threadIdx.x >> 6);
  const int lane = threadIdx.x & 63;
  const int q = lane >> 4;       // quarter 0..3
  const int l = lane & 15;       // lane-in-quarter: cols l*8..l*8+7
  if (node >= NN) return;
  const int dcnt = cnt[node];
  const int n = dcnt < CAP ? dcnt : CAP;
  const int* row = ell + (size_t)node * CAP;
  float s[8] = {0.f, 0.f, 0.f, 0.f, 0.f, 0.f, 0.f, 0.f};
  int p = q;
  for (; p + 12 < n; p += 16) {  // 4 independent row loads in flight
    uint2 w0 = *(const uint2*)(h8 + (size_t)row[p] * DIM + l * 8);
    uint2 w1 = *(const uint2*)(h8 + (size_t)row[p + 4] * DIM + l * 8);
    uint2 w2 = *(const uint2*)(h8 + (size_t)row[p + 8] * DIM + l * 8);
    uint2 w3 = *(const uint2*)(h8 + (size_t)row[p + 12] * DIM + l * 8);
    acc_fp8x8(s, w0);
    acc_fp8x8(s, w1);
    acc_fp8x8(s, w2);
    acc_fp8x8(s, w3);
  }
  for (; p < n; p += 4) {
    uint2 w0 = *(const uint2*)(h8 + (size_t)row[p] * DIM + l * 8);
    acc_fp8x8(s, w0);
  }
#pragma unroll
  for (int i = 0; i < 8; ++i) {
    s[i] += __shfl_xor(s[i], 16, 64);
    s[i] += __shfl_xor(s[i], 32, 64);
  }
  if (q == 0) {
    if (dcnt > CAP) {  // overflow fixup: scan tiny list (expected empty)
      int no = *novf;
      if (no > OVF_CAP) no = OVF_CAP;
      for (int i = 0; i < no; ++i) {
        if (ovf[i * 2 + 1] == node) {
          uint2 w0 = *(const uint2*)(h8 + (size_t)ovf[i * 2] * DIM + l * 8);
          acc_fp8x8(s, w0);
        }
      }
    }
    const float rd = 1.0f / fmaxf((float)dcnt, 1.0f);
    uint4 o;
    o.x = pk2(s[0] * rd, s[1] * rd);
    o.y = pk2(s[2] * rd, s[3] * rd);
    o.z = pk2(s[4] * rd, s[5] * rd);
    o.w = pk2(s[6] * rd, s[7] * rd);
    *(uint4*)(ahi + (size_t)node * DIM + l * 8) = o;
  }
}

// ---------------------------------------------------------------------------
// Dense via MFMA: out = act(agg_bf16 @ Wl + bl + h_bf16 @ Wr).
// Pure bf16-plane loads (2 x 16B per fragment pair -> 4 MFMAs), no in-loop
// conversion (round-14's f32-load + cvt chain halved dense throughput).
// WP (layer 1): epilogue writes result IN-PLACE over hb (bf16) and h8 (fp8)
//   -- safe: each block reads only its own 64 rows (before __syncthreads);
//   gather-1 has already completed; no other block reads these rows.
// WOUT (layer 2): writes f32 out only.
// ---------------------------------------------------------------------------
template <bool RELU, bool WP, bool WOUT>
__global__ __launch_bounds__(256, 2) void dense_mfma_kernel(
    const unsigned short* __restrict__ ahi, unsigned short* hb,
    const unsigned short* __restrict__ Wt, const float* __restrict__ bl,
    float* __restrict__ out, unsigned char* ph8, int n) {
  const int t = threadIdx.x;
  const int wave = t >> 6, lane = t & 63;
  const int l15 = lane & 15, l4 = lane >> 4;
  const int base = blockIdx.x * 64;

  bf16x8 bfr[2][4][2];
#pragma unroll
  for (int mat = 0; mat < 2; ++mat)
#pragma unroll
    for (int kt = 0; kt < 4; ++kt)
#pragma unroll
      for (int ntl = 0; ntl < 2; ++ntl) {
        int ncol = (wave * 2 + ntl) * 16 + l15;
        int k0 = kt * 32 + l4 * 8;
        bfr[mat][kt][ntl] = *(const bf16x8*)(Wt + ((size_t)(mat * 128 + ncol)) * 128 + k0);
      }

  f32x4 acc[4][2];
#pragma unroll
  for (int ntl = 0; ntl < 2; ++ntl) {
    float b = bl[(wave * 2 + ntl) * 16 + l15];
#pragma unroll
    for (int rt = 0; rt < 4; ++rt) {
      f32x4 ib = {b, b, b, b};
      acc[rt][ntl] = ib;
    }
  }

#pragma unroll
  for (int kt = 0; kt < 4; ++kt) {
    const int k0 = kt * 32 + l4 * 8;
#pragma unroll
    for (int rt = 0; rt < 4; ++rt) {
      int row = base + rt * 16 + l15;
      if (row >= n) row = n - 1;  // clamp: padded rows computed but never stored
      const size_t off = (size_t)row * DIM + k0;
      bf16x8 a8 = *(const bf16x8*)(ahi + off);
      bf16x8 hh8 = *(const bf16x8*)(hb + off);
#pragma unroll
      for (int ntl = 0; ntl < 2; ++ntl) {
        acc[rt][ntl] = __builtin_amdgcn_mfma_f32_16x16x32_bf16(a8, bfr[0][kt][ntl], acc[rt][ntl], 0, 0, 0);
        acc[rt][ntl] = __builtin_amdgcn_mfma_f32_16x16x32_bf16(hh8, bfr[1][kt][ntl], acc[rt][ntl], 0, 0, 0);
      }
    }
  }

  __syncthreads();  // all hb reads complete before the in-place plane writes

#pragma unroll
  for (int rt = 0; rt < 4; ++rt)
#pragma unroll
    for (int ntl = 0; ntl < 2; ++ntl) {
      const int col = (wave * 2 + ntl) * 16 + l15;
#pragma unroll
      for (int r = 0; r < 4; ++r) {
        int row = base + rt * 16 + l4 * 4 + r;
        if (row < n) {
          float v = acc[rt][ntl][r];
          if (RELU) v = fmaxf(v, 0.f);
          const size_t off = (size_t)row * DIM + col;
          if (WOUT) out[off] = v;
          if (WP) {
            hb[off] = f2bf(v);
            ph8[off] = (unsigned char)(f2fp8_pair<false>(v, v, 0) & 0xFF);
          }
        }
      }
    }
}

// ---------------------------------------------------------------------------
extern "C" void kernel_launch(void* const* d_in, const int* in_sizes, int n_in,
                              void* d_out, int out_size, void* d_ws, size_t ws_size,
                              hipStream_t stream) {
  const float* x   = (const float*)d_in[0];
  const void* edges = d_in[1];
  const float* W1l = (const float*)d_in[2];
  const float* b1l = (const float*)d_in[3];
  const float* W1r = (const float*)d_in[4];
  const float* W2l = (const float*)d_in[5];
  const float* b2l = (const float*)d_in[6];
  const float* W2r = (const float*)d_in[7];
  float* out = (float*)d_out;

  // ---- workspace layout (~85 MB)
  //  * part (24.5 MB) aliases ahi (25.6 MB): part dead after partB, ahi
  //    first written by gather-1.
  //  * h1 planes overwrite x planes IN-PLACE in dense-1's epilogue.
  char* p = (char*)d_ws;
  unsigned short* Wt1 = (unsigned short*)p;               p += 2 * 128 * 128 * 2;
  unsigned short* Wt2 = (unsigned short*)p;               p += 2 * 128 * 128 * 2;
  int* cnt   = (int*)p;                                   p += (size_t)NN * 4;
  int* bcnt2 = (int*)p;                                   p += (size_t)NB * EDGE_BLKS * 4;
  int* novf  = (int*)p;                                   p += 4;
  p = (char*)(((uintptr_t)p + 15) & ~(uintptr_t)15);
  int* ovf = (int*)p;                                     p += (size_t)OVF_CAP * 2 * 4;
  p = (char*)(((uintptr_t)p + 255) & ~(uintptr_t)255);
  int* ell = (int*)p;                                     p += (size_t)NB * 256 * CAP * 4;
  p = (char*)(((uintptr_t)p + 255) & ~(uintptr_t)255);
  unsigned short* ahi = (unsigned short*)p;               p += (size_t)NN * DIM * 2;
  unsigned short* hb = (unsigned short*)p;                p += (size_t)NN * DIM * 2;  // x/h1 bf16
  unsigned char* h8 = (unsigned char*)p;                  p += (size_t)NN * DIM;      // x/h1 fp8
  unsigned* part = (unsigned*)ahi;  // alias (disjoint lifetimes); 24.5 MB <= 25.6 MB

  // zero novf only (bcnt2 fully written by partA; cnt by partB)
  (void)hipMemsetAsync(novf, 0, 4, stream);

  // partition (private segments, no global atomics) + weight/x prep, one grid
  partA_prep_kernel<<<EDGE_BLKS + NPREP_W + NPREP_X, ATHREADS, 0, stream>>>(
      edges, bcnt2, part, novf, ovf, x, W1l, W1r, W2l, W2r, Wt1, Wt2, hb, h8);
  partB_kernel<<<NB, 256, 0, stream>>>(bcnt2, part, cnt, ell, novf, ovf);

  const int gather_blocks = (NN + 3) / 4;
  const int dense_blocks = (NN + 63) / 64;

  // ---- layer 1: h1 = relu(mean_agg(x) @ W1l + b1l + x @ W1r)
  //      -> bf16 plane (over hb) + fp8 plane (over h8); no f32 write
  gather_ell_kernel<<<gather_blocks, 256, 0, stream>>>(cnt, ell, h8, ahi, novf, ovf);
  dense_mfma_kernel<true, true, false><<<dense_blocks, 256, 0, stream>>>(
      ahi, hb, Wt1, b1l, out, h8, NN);

  // ---- layer 2: out = mean_agg(h1) @ W2l + b2l + h1 @ W2r -> f32 out
  gather_ell_kernel<<<gather_blocks, 256, 0, stream>>>(cnt, ell, h8, ahi, novf, ovf);
  dense_mfma_kernel<false, false, true><<<dense_blocks, 256, 0, stream>>>(
      ahi, hb, Wt2, b2l, out, nullptr, NN);
}

// Round 19
// 231.016 us; speedup vs baseline: 1.0613x; 1.0195x over previous
//
#include <hip/hip_runtime.h>
#include <cstdint>
#include <cstddef>

#define NN 100000
#define EE 1600000
#define DIM 128
#define CAP 48        // ELL row capacity (mean deg 16; P(deg>48) ~ 5e-11 per node)
#define OVF_CAP 512   // overflow edge capacity (expected 0 used)

#define NB 391        // dst buckets of 256 nodes: ceil(100000/256)
#define BCAP 4608     // per-bucket partition capacity (mean 4092, +8 sigma)
#define SLOTS 32      // LDS staging slots per bucket
#define FLUSH_AT 16   // flush threshold (entries)
#define ACHUNK 4096   // edges per phase-A partition block
#define ATHREADS 512

#define NPREP_W 128                          // weight-prep blocks (65536/512)
#define NPREP_X ((NN * DIM / 4) / ATHREADS)  // x-cast blocks (6250)

#if __has_builtin(__builtin_amdgcn_cvt_pk_f32_fp8) && __has_builtin(__builtin_amdgcn_cvt_pk_fp8_f32)
#define HAVE_FP8 1
#else
#define HAVE_FP8 0
#endif

typedef __attribute__((ext_vector_type(8))) short bf16x8;
typedef __attribute__((ext_vector_type(4))) float f32x4;
typedef __attribute__((ext_vector_type(2))) float f32x2;

__device__ __forceinline__ unsigned short f2bf(float f) {
  union { float f; uint32_t u; } v; v.f = f;
  uint32_t r = v.u + 0x7FFF + ((v.u >> 16) & 1);  // RNE to bf16
  return (unsigned short)(r >> 16);
}
__device__ __forceinline__ uint32_t pk2(float a, float b) {
  return (uint32_t)f2bf(a) | ((uint32_t)f2bf(b) << 16);
}

// ---- fp8 e4m3fn helpers (HW path + software fallback) ----------------------
// NOTE: the builtin's word-select arg must be a LITERAL constant -> template.
template <bool HI>
__device__ __forceinline__ uint32_t f2fp8_pair(float a, float b, uint32_t old) {
#if HAVE_FP8
  return (uint32_t)__builtin_amdgcn_cvt_pk_fp8_f32(a, b, (int)old, HI);
#else
  auto enc = [](float f) -> uint32_t {
    union { float f; uint32_t u; } v; v.f = f;
    uint32_t s = (v.u >> 31) << 7;
    uint32_t m = v.u & 0x7FFFFFFF;
    if (m < 0x3C000000u) {  // < 2^-7: subnormal territory
      union { uint32_t u; float f; } w; w.u = m;
      int q = (int)(w.f * 512.0f + 0.5f);
      if (q > 7) return s | (1u << 3);
      return s | (uint32_t)q;
    }
    uint32_t u2 = m + 0x00080000u;  // round into mantissa bit 20
    int e = (int)(u2 >> 23) - 127;
    if (e > 8) return s | 0x7E;  // clamp to 448
    return s | ((uint32_t)(e + 7) << 3) | ((u2 >> 20) & 7);
  };
  uint32_t pr = enc(a) | (enc(b) << 8);
  return HI ? ((old & 0x0000FFFFu) | (pr << 16)) : ((old & 0xFFFF0000u) | pr);
#endif
}

// round-16 scalar accumulate (8 independent f32 chains -- round-17's packed
// variant REGRESSED: longer cvt->pk_add dependency chains)
__device__ __forceinline__ void acc_fp8x8(float* s, uint2 w) {
#if HAVE_FP8
  f32x2 f;
  f = __builtin_amdgcn_cvt_pk_f32_fp8((int)w.x, false); s[0] += f.x; s[1] += f.y;
  f = __builtin_amdgcn_cvt_pk_f32_fp8((int)w.x, true);  s[2] += f.x; s[3] += f.y;
  f = __builtin_amdgcn_cvt_pk_f32_fp8((int)w.y, false); s[4] += f.x; s[5] += f.y;
  f = __builtin_amdgcn_cvt_pk_f32_fp8((int)w.y, true);  s[6] += f.x; s[7] += f.y;
#else
  auto dec = [](uint32_t b) -> float {
    uint32_t sg = (b >> 7) & 1, e = (b >> 3) & 15, m = b & 7;
    if (e == 0) return (sg ? -1.f : 1.f) * (float)m * 0.001953125f;  // m * 2^-9
    union { uint32_t u; float f; } w;
    w.u = (sg << 31) | ((e + 120) << 23) | (m << 20);
    return w.f;
  };
#pragma unroll
  for (int i = 0; i < 4; ++i) s[i] += dec((w.x >> (i * 8)) & 0xFF);
#pragma unroll
  for (int i = 0; i < 4; ++i) s[4 + i] += dec((w.y >> (i * 8)) & 0xFF);
#endif
}

// ---------------------------------------------------------------------------
// partA_prep (round-16 form -- round-18's private-segment variant regressed
// on write-allocate traffic): blocks < NB partition edges into dst-buckets
// (LDS staging, per-thread flush); blocks >= NB do prep.
// pack = s | ((d & 255) << 17)   (s < 2^17)
// ---------------------------------------------------------------------------
__global__ __launch_bounds__(ATHREADS) void partA_prep_kernel(
    const void* __restrict__ edges, int* __restrict__ bcnt,
    unsigned* __restrict__ part, int* __restrict__ novf, int* __restrict__ ovf,
    const float* __restrict__ x,
    const float* __restrict__ W1l, const float* __restrict__ W1r,
    const float* __restrict__ W2l, const float* __restrict__ W2r,
    unsigned short* __restrict__ Wt1, unsigned short* __restrict__ Wt2,
    unsigned short* __restrict__ xb, unsigned char* __restrict__ x8) {
  __shared__ unsigned stage[NB][SLOTS + 1];  // +1 pad: de-alias flush banks
  __shared__ int scnt[NB];
  __shared__ int sh_i64;
  const int t = threadIdx.x;

  if (blockIdx.x >= NB) {  // ---- prep path (no LDS use) ----
    int bid = blockIdx.x - NB;
    if (bid < NPREP_W) {
      int idx = bid * ATHREADS + t;  // 65536 total
      int layer = idx >> 15;
      int rest = idx & 32767;
      int mat = rest >> 14;
      int r = rest & 16383;
      int k = r >> 7, n = r & 127;
      const float* W = layer ? (mat ? W2r : W2l) : (mat ? W1r : W1l);
      unsigned short* Wt = layer ? Wt2 : Wt1;
      Wt[((size_t)(mat * 128 + n)) * 128 + k] = f2bf(W[k * 128 + n]);
    } else {
      int i = (bid - NPREP_W) * ATHREADS + t;  // one float4 per thread
      if (i < NN * DIM / 4) {
        f32x4 v = ((const f32x4*)x)[i];
        ushort4 hb;
        hb.x = f2bf(v[0]); hb.y = f2bf(v[1]); hb.z = f2bf(v[2]); hb.w = f2bf(v[3]);
        ((ushort4*)xb)[i] = hb;
        uint32_t pk = f2fp8_pair<false>(v[0], v[1], 0);
        pk = f2fp8_pair<true>(v[2], v[3], pk);
        ((uint32_t*)x8)[i] = pk;
      }
    }
    return;
  }

  // ---- partition path ----
  for (int b = t; b < NB; b += ATHREADS) scnt[b] = 0;
  if (t < 64) {
    // int64 little-endian => odd 32-bit words of first 64 entries all zero;
    // int32 => those words are random src values, all-zero impossible.
    int v = ((const int*)edges)[2 * t + 1];
    unsigned long long m = __ballot(v != 0);
    if (t == 0) sh_i64 = (m == 0ull) ? 1 : 0;
  }
  __syncthreads();
  const int i64 = sh_i64;
  const long long ebase = (long long)blockIdx.x * ACHUNK;
  const int nrounds = ACHUNK / ATHREADS;
  for (int r = 0; r < nrounds; ++r) {
    long long e = ebase + (long long)r * ATHREADS + t;
    if (e < EE) {
      int s, d;
      if (i64) {
        s = (int)((const long long*)edges)[e];
        d = (int)((const long long*)edges)[(long long)EE + e];
      } else {
        s = ((const int*)edges)[e];
        d = ((const int*)edges)[(long long)EE + e];
      }
      if ((unsigned)s < NN && (unsigned)d < NN) {
        int b = d >> 8;
        unsigned pk = (unsigned)s | ((unsigned)(d & 255) << 17);
        int pos = atomicAdd(&scnt[b], 1);
        if (pos < SLOTS) {
          stage[b][pos] = pk;
        } else {  // stage overflow (rare): direct append
          int g = atomicAdd(&bcnt[b], 1);
          if (g < BCAP) part[(size_t)b * BCAP + g] = pk;
          else { int oi = atomicAdd(novf, 1); if (oi < OVF_CAP) { ovf[oi*2] = s; ovf[oi*2+1] = d; } }
        }
      }
    }
    __syncthreads();
    const bool last = (r == nrounds - 1);
    for (int b = t; b < NB; b += ATHREADS) {  // per-thread flush (parallel chains)
      int c = scnt[b];
      if (c > SLOTS) c = SLOTS;
      if (c > 0 && (last || c >= FLUSH_AT)) {
        int g = atomicAdd(&bcnt[b], c);
        for (int i = 0; i < c; ++i) {
          int gp = g + i;
          unsigned pk = stage[b][i];
          if (gp < BCAP) {
            part[(size_t)b * BCAP + gp] = pk;
          } else {
            int oi = atomicAdd(novf, 1);
            if (oi < OVF_CAP) { ovf[oi*2] = (int)(pk & 0x1FFFF); ovf[oi*2+1] = (b << 8) | (int)(pk >> 17); }
          }
        }
        scnt[b] = 0;
      }
    }
    __syncthreads();
  }
}

// ---------------------------------------------------------------------------
// Phase B (round-16 form): per bucket (256 nodes), build ELL rows in LDS
// (LDS atomics), write densely coalesced. Also emits cnt (degree).
// ---------------------------------------------------------------------------
__global__ __launch_bounds__(256) void partB_kernel(
    const int* __restrict__ bcnt, const unsigned* __restrict__ part,
    int* __restrict__ cnt, int* __restrict__ ell,
    int* __restrict__ novf, int* __restrict__ ovf) {
  __shared__ int lcnt[256];
  __shared__ int lell[256 * CAP];  // 48 KB
  const int t = threadIdx.x;
  const int b = blockIdx.x;
  lcnt[t] = 0;
  __syncthreads();
  int n = bcnt[b];
  if (n > BCAP) n = BCAP;
  for (int i = t; i < n; i += 256) {
    unsigned pk = part[(size_t)b * BCAP + i];
    int s = (int)(pk & 0x1FFFF);
    int dl = (int)(pk >> 17);
    int pos = atomicAdd(&lcnt[dl], 1);
    if (pos < CAP) lell[dl * CAP + pos] = s;
    else { int oi = atomicAdd(novf, 1); if (oi < OVF_CAP) { ovf[oi*2] = s; ovf[oi*2+1] = (b << 8) | dl; } }
  }
  __syncthreads();
  int4* dst = (int4*)(ell + (size_t)b * 256 * CAP);
  const int4* src = (const int4*)lell;
#pragma unroll
  for (int i = 0; i < 256 * CAP / 4 / 256; ++i) dst[t + i * 256] = src[t + i * 256];
  int node = b * 256 + t;
  if (node < NN) cnt[node] = lcnt[t];
}

// ---------------------------------------------------------------------------
// Gather-aggregate from ELL over fp8 rows (128 B = ONE cache line per nbr).
// Round-16 form (empirical optimum across r10/r12/r17 attempts).
// ---------------------------------------------------------------------------
__global__ __launch_bounds__(256) void gather_ell_kernel(
    const int* __restrict__ cnt, const int* __restrict__ ell,
    const unsigned char* __restrict__ h8, unsigned short* __restrict__ ahi,
    const int* __restrict__ novf, const int* __restrict__ ovf) {
  const int node = blockIdx.x * 4 + (threadIdx.x >> 6);
  const int lane = threadIdx.x & 63;
  const int q = lane >> 4;       // quarter 0..3
  const int l = lane & 15;       // lane-in-quarter: cols l*8..l*8+7
  if (node >= NN) return;
  const int dcnt = cnt[node];
  const int n = dcnt < CAP ? dcnt : CAP;
  const int* row = ell + (size_t)node * CAP;
  float s[8] = {0.f, 0.f, 0.f, 0.f, 0.f, 0.f, 0.f, 0.f};
  int p = q;
  for (; p + 12 < n; p += 16) {  // 4 independent row loads in flight
    uint2 w0 = *(const uint2*)(h8 + (size_t)row[p] * DIM + l * 8);
    uint2 w1 = *(const uint2*)(h8 + (size_t)row[p + 4] * DIM + l * 8);
    uint2 w2 = *(const uint2*)(h8 + (size_t)row[p + 8] * DIM + l * 8);
    uint2 w3 = *(const uint2*)(h8 + (size_t)row[p + 12] * DIM + l * 8);
    acc_fp8x8(s, w0);
    acc_fp8x8(s, w1);
    acc_fp8x8(s, w2);
    acc_fp8x8(s, w3);
  }
  for (; p < n; p += 4) {
    uint2 w0 = *(const uint2*)(h8 + (size_t)row[p] * DIM + l * 8);
    acc_fp8x8(s, w0);
  }
#pragma unroll
  for (int i = 0; i < 8; ++i) {
    s[i] += __shfl_xor(s[i], 16, 64);
    s[i] += __shfl_xor(s[i], 32, 64);
  }
  if (q == 0) {
    if (dcnt > CAP) {  // overflow fixup: scan tiny list (expected empty)
      int no = *novf;
      if (no > OVF_CAP) no = OVF_CAP;
      for (int i = 0; i < no; ++i) {
        if (ovf[i * 2 + 1] == node) {
          uint2 w0 = *(const uint2*)(h8 + (size_t)ovf[i * 2] * DIM + l * 8);
          acc_fp8x8(s, w0);
        }
      }
    }
    const float rd = 1.0f / fmaxf((float)dcnt, 1.0f);
    uint4 o;
    o.x = pk2(s[0] * rd, s[1] * rd);
    o.y = pk2(s[2] * rd, s[3] * rd);
    o.z = pk2(s[4] * rd, s[5] * rd);
    o.w = pk2(s[6] * rd, s[7] * rd);
    *(uint4*)(ahi + (size_t)node * DIM + l * 8) = o;
  }
}

// ---------------------------------------------------------------------------
// Dense via MFMA: out = act(agg_bf16 @ Wl + bl + h_bf16 @ Wr).
// NEW: explicit software pipeline. Weights hoisted once (64 VGPR held live);
// A/H fragments double-buffered per-rt: rt+1's 8 loads issue while rt's 16
// MFMAs run. All buffer indices compile-time constant (full unroll).
// WP (layer 1): epilogue writes result IN-PLACE over hb (bf16) and h8 (fp8).
// WOUT (layer 2): writes f32 out only.
// ---------------------------------------------------------------------------
template <bool RELU, bool WP, bool WOUT>
__global__ __launch_bounds__(256, 2) void dense_mfma_kernel(
    const unsigned short* __restrict__ ahi, unsigned short* hb,
    const unsigned short* __restrict__ Wt, const float* __restrict__ bl,
    float* __restrict__ out, unsigned char* ph8, int n) {
  const int t = threadIdx.x;
  const int wave = t >> 6, lane = t & 63;
  const int l15 = lane & 15, l4 = lane >> 4;
  const int base = blockIdx.x * 64;

  // weights: held live for the whole kernel (16 x bf16x8 = 64 VGPR)
  bf16x8 bfr[2][4][2];
#pragma unroll
  for (int mat = 0; mat < 2; ++mat)
#pragma unroll
    for (int kt = 0; kt < 4; ++kt)
#pragma unroll
      for (int ntl = 0; ntl < 2; ++ntl) {
        int ncol = (wave * 2 + ntl) * 16 + l15;
        int k0 = kt * 32 + l4 * 8;
        bfr[mat][kt][ntl] = *(const bf16x8*)(Wt + ((size_t)(mat * 128 + ncol)) * 128 + k0);
      }

  f32x4 acc[4][2];
#pragma unroll
  for (int ntl = 0; ntl < 2; ++ntl) {
    float b = bl[(wave * 2 + ntl) * 16 + l15];
#pragma unroll
    for (int rt = 0; rt < 4; ++rt) {
      f32x4 ib = {b, b, b, b};
      acc[rt][ntl] = ib;
    }
  }

  // row base addresses (clamped; padded rows computed but never stored)
  auto row_off = [&](int rt) -> size_t {
    int row = base + rt * 16 + l15;
    if (row >= n) row = n - 1;
    return (size_t)row * DIM + l4 * 8;
  };

  // double-buffered A/H fragments: 2 x 4kt x 2 = 16 x bf16x8 = 64 VGPR
  bf16x8 a_b[2][4], h_b[2][4];
  {
    const size_t o0 = row_off(0);
#pragma unroll
    for (int kt = 0; kt < 4; ++kt) {
      a_b[0][kt] = *(const bf16x8*)(ahi + o0 + kt * 32);
      h_b[0][kt] = *(const bf16x8*)(hb + o0 + kt * 32);
    }
  }
#pragma unroll
  for (int rt = 0; rt < 4; ++rt) {
    if (rt < 3) {  // prefetch rt+1 while rt's MFMAs run
      const size_t on = row_off(rt + 1);
#pragma unroll
      for (int kt = 0; kt < 4; ++kt) {
        a_b[(rt + 1) & 1][kt] = *(const bf16x8*)(ahi + on + kt * 32);
        h_b[(rt + 1) & 1][kt] = *(const bf16x8*)(hb + on + kt * 32);
      }
    }
#pragma unroll
    for (int kt = 0; kt < 4; ++kt)
#pragma unroll
      for (int ntl = 0; ntl < 2; ++ntl) {
        acc[rt][ntl] = __builtin_amdgcn_mfma_f32_16x16x32_bf16(a_b[rt & 1][kt], bfr[0][kt][ntl], acc[rt][ntl], 0, 0, 0);
        acc[rt][ntl] = __builtin_amdgcn_mfma_f32_16x16x32_bf16(h_b[rt & 1][kt], bfr[1][kt][ntl], acc[rt][ntl], 0, 0, 0);
      }
  }

  __syncthreads();  // all hb reads complete before the in-place plane writes

#pragma unroll
  for (int rt = 0; rt < 4; ++rt)
#pragma unroll
    for (int ntl = 0; ntl < 2; ++ntl) {
      const int col = (wave * 2 + ntl) * 16 + l15;
#pragma unroll
      for (int r = 0; r < 4; ++r) {
        int row = base + rt * 16 + l4 * 4 + r;
        if (row < n) {
          float v = acc[rt][ntl][r];
          if (RELU) v = fmaxf(v, 0.f);
          const size_t off = (size_t)row * DIM + col;
          if (WOUT) out[off] = v;
          if (WP) {
            hb[off] = f2bf(v);
            ph8[off] = (unsigned char)(f2fp8_pair<false>(v, v, 0) & 0xFF);
          }
        }
      }
    }
}

// ---------------------------------------------------------------------------
extern "C" void kernel_launch(void* const* d_in, const int* in_sizes, int n_in,
                              void* d_out, int out_size, void* d_ws, size_t ws_size,
                              hipStream_t stream) {
  const float* x   = (const float*)d_in[0];
  const void* edges = d_in[1];
  const float* W1l = (const float*)d_in[2];
  const float* b1l = (const float*)d_in[3];
  const float* W1r = (const float*)d_in[4];
  const float* W2l = (const float*)d_in[5];
  const float* b2l = (const float*)d_in[6];
  const float* W2r = (const float*)d_in[7];
  float* out = (float*)d_out;

  // ---- workspace layout (~84 MB)
  //  * part (7.2 MB) aliases ahi (25.6 MB): part dead after partB, ahi first
  //    written by gather-1.
  //  * h1 planes overwrite x planes IN-PLACE in dense-1's epilogue (each
  //    block touches only rows it already consumed; gather-1 done).
  char* p = (char*)d_ws;
  unsigned short* Wt1 = (unsigned short*)p;               p += 2 * 128 * 128 * 2;
  unsigned short* Wt2 = (unsigned short*)p;               p += 2 * 128 * 128 * 2;
  int* cnt  = (int*)p;                                    p += (size_t)NN * 4;
  int* bcnt = (int*)p;                                    p += (size_t)NB * 4;
  int* novf = (int*)p;                                    p += 4;
  p = (char*)(((uintptr_t)p + 15) & ~(uintptr_t)15);
  int* ovf = (int*)p;                                     p += (size_t)OVF_CAP * 2 * 4;
  p = (char*)(((uintptr_t)p + 255) & ~(uintptr_t)255);
  int* ell = (int*)p;                                     p += (size_t)NB * 256 * CAP * 4;
  p = (char*)(((uintptr_t)p + 255) & ~(uintptr_t)255);
  unsigned short* ahi = (unsigned short*)p;               p += (size_t)NN * DIM * 2;
  unsigned short* hb = (unsigned short*)p;                p += (size_t)NN * DIM * 2;  // x/h1 bf16
  unsigned char* h8 = (unsigned char*)p;                  p += (size_t)NN * DIM;      // x/h1 fp8
  unsigned* part = (unsigned*)ahi;  // alias (disjoint lifetimes)

  // zero bcnt + novf in one memset (cnt fully rewritten by partB)
  (void)hipMemsetAsync(bcnt, 0, ((size_t)NB + 1) * 4, stream);

  // partition + weight/x prep in one grid (prep fills idle CUs)
  partA_prep_kernel<<<NB + NPREP_W + NPREP_X, ATHREADS, 0, stream>>>(
      edges, bcnt, part, novf, ovf, x, W1l, W1r, W2l, W2r, Wt1, Wt2, hb, h8);
  partB_kernel<<<NB, 256, 0, stream>>>(bcnt, part, cnt, ell, novf, ovf);

  const int gather_blocks = (NN + 3) / 4;
  const int dense_blocks = (NN + 63) / 64;

  // ---- layer 1: h1 = relu(mean_agg(x) @ W1l + b1l + x @ W1r)
  //      -> bf16 plane (over hb) + fp8 plane (over h8); no f32 write
  gather_ell_kernel<<<gather_blocks, 256, 0, stream>>>(cnt, ell, h8, ahi, novf, ovf);
  dense_mfma_kernel<true, true, false><<<dense_blocks, 256, 0, stream>>>(
      ahi, hb, Wt1, b1l, out, h8, NN);

  // ---- layer 2: out = mean_agg(h1) @ W2l + b2l + h1 @ W2r -> f32 out
  gather_ell_kernel<<<gather_blocks, 256, 0, stream>>>(cnt, ell, h8, ahi, novf, ovf);
  dense_mfma_kernel<false, false, true><<<dense_blocks, 256, 0, stream>>>(
      ahi, hb, Wt2, b2l, out, nullptr, NN);
}